// Round 3
// baseline (1872.932 us; speedup 1.0000x reference)
//
#include <hip/hip_runtime.h>
#include <math.h>

typedef unsigned short u16;
typedef __bf16 bf16;
typedef bf16 bf16x8 __attribute__((ext_vector_type(8)));
typedef float f32x4 __attribute__((ext_vector_type(4)));

__device__ __forceinline__ float b2f(u16 u) {
    union { unsigned int i; float f; } w;
    w.i = ((unsigned int)u) << 16;
    return w.f;
}
__device__ __forceinline__ u16 f2b(float f) {
    union { float f; unsigned int i; } w;
    w.f = f;
    unsigned int x = w.i;
    return (u16)((x + 0x7fffu + ((x >> 16) & 1u)) >> 16);
}

// ---------------------------------------------------------- input dtype sniff
// f32 inputs: low u16 of each word decodes as bf16 to huge/NaN values.
__global__ __launch_bounds__(256)
void sniff_kernel(const u16* __restrict__ w, int* __restrict__ flag) {
    __shared__ int s;
    if (threadIdx.x == 0) s = 0;
    __syncthreads();
    int big = 0;
    for (int i = threadIdx.x; i < 2048; i += 256) {
        float v = fabsf(b2f(w[2 * i]));
        if (!(v < 1e6f)) big = 1;
    }
    if (big) atomicOr(&s, 1);
    __syncthreads();
    if (threadIdx.x == 0) flag[0] = s;
}

// ------------------------------------------------- weight convert -> bf16 ws
__global__ __launch_bounds__(256)
void cvt_kernel(const void* __restrict__ src, u16* __restrict__ dst, int n,
                const int* __restrict__ flag) {
    int i = (blockIdx.x * 256 + threadIdx.x) * 8;
    if (i >= n) return;
    if (flag[0]) {
        const float* s = (const float*)src;
        float4 a = *(const float4*)(s + i);
        float4 b = *(const float4*)(s + i + 4);
        ushort4 o1 = {f2b(a.x), f2b(a.y), f2b(a.z), f2b(a.w)};
        ushort4 o2 = {f2b(b.x), f2b(b.y), f2b(b.z), f2b(b.w)};
        *(ushort4*)(dst + i) = o1;
        *(ushort4*)(dst + i + 4) = o2;
    } else {
        const ushort4* s = (const ushort4*)src;
        *(ushort4*)(dst + i) = s[i / 4];
        *(ushort4*)(dst + i + 4) = s[i / 4 + 1];
    }
}

// ---------------------------------------------------------------- silu(c)
__global__ __launch_bounds__(256)
void silu_kernel(const void* __restrict__ c, const int* __restrict__ flag,
                 float* __restrict__ cactf, float* __restrict__ out_cact) {
    int i = blockIdx.x * 256 + threadIdx.x;
    if (i < 8 * 1024) {
        float v = flag[0] ? ((const float*)c)[i] : b2f(((const u16*)c)[i]);
        float s = v / (1.f + expf(-v));
        cactf[i] = s;
        out_cact[i] = s;
    }
}

// ------------------------------------------- cmod = silu(c) @ w_mod + b_mod
__global__ __launch_bounds__(256)
void cmod_kernel(const float* __restrict__ cactf, const void* __restrict__ w_mod,
                 const void* __restrict__ b_mod, const int* __restrict__ flag,
                 float* __restrict__ cmodf, float* __restrict__ out_cmod,
                 float* __restrict__ out_shift, float* __restrict__ out_scale) {
    int j = blockIdx.x * 256 + threadIdx.x;   // 0..6143
    int b = blockIdx.y;                       // 0..7
    const int isf = flag[0];
    const float* ca = cactf + b * 1024;
    float acc = isf ? ((const float*)b_mod)[j] : b2f(((const u16*)b_mod)[j]);
    if (isf) {
        const float* wf = (const float*)w_mod;
#pragma unroll 8
        for (int k = 0; k < 1024; ++k)
            acc += ca[k] * wf[(size_t)k * 6144 + j];
    } else {
        const u16* wb = (const u16*)w_mod;
#pragma unroll 8
        for (int k = 0; k < 1024; ++k)
            acc += ca[k] * b2f(wb[(size_t)k * 6144 + j]);
    }
    cmodf[b * 6144 + j] = acc;
    out_cmod[b * 6144 + j] = acc;
    if (j < 1024) out_shift[b * 1024 + j] = acc;
    else if (j < 2048) out_scale[b * 1024 + (j - 1024)] = acc;
}

// -------------------------------------------------- LayerNorm + modulate
__global__ __launch_bounds__(256)
void ln_mod_kernel(const void* __restrict__ xin, const int* __restrict__ flag,
                   int force_f32, const float* __restrict__ cmodf,
                   int shift_off, int scale_off, float* __restrict__ out_norm,
                   float* __restrict__ out_mod, u16* __restrict__ ws_mod) {
    const int row = blockIdx.x;          // 0..8191
    const int tid = threadIdx.x;         // 256
    const int bidx = row >> 10;
    const int isf = force_f32 | flag[0];
    const size_t base = (size_t)row * 1024 + tid * 4;
    float v[4];
    if (isf) {
        float4 f = *reinterpret_cast<const float4*>((const float*)xin + base);
        v[0] = f.x; v[1] = f.y; v[2] = f.z; v[3] = f.w;
    } else {
        ushort4 u = *reinterpret_cast<const ushort4*>((const u16*)xin + base);
        v[0] = b2f(u.x); v[1] = b2f(u.y); v[2] = b2f(u.z); v[3] = b2f(u.w);
    }
    float s = v[0] + v[1] + v[2] + v[3];
#pragma unroll
    for (int o = 32; o; o >>= 1) s += __shfl_xor(s, o, 64);
    __shared__ float red1[4], red2[4];
    const int lane = tid & 63, wv = tid >> 6;
    if (lane == 0) red1[wv] = s;
    __syncthreads();
    float mean = (red1[0] + red1[1] + red1[2] + red1[3]) * 0.0009765625f;
    float d0 = v[0] - mean, d1 = v[1] - mean, d2 = v[2] - mean, d3 = v[3] - mean;
    float sq = d0 * d0 + d1 * d1 + d2 * d2 + d3 * d3;
#pragma unroll
    for (int o = 32; o; o >>= 1) sq += __shfl_xor(sq, o, 64);
    if (lane == 0) red2[wv] = sq;
    __syncthreads();
    float var = (red2[0] + red2[1] + red2[2] + red2[3]) * 0.0009765625f;
    float rs = rsqrtf(var + 1e-6f);
    float xn[4] = {d0 * rs, d1 * rs, d2 * rs, d3 * rs};
    const int d = tid * 4;
    const float* cb = cmodf + bidx * 6144;
    float4 fn = {xn[0], xn[1], xn[2], xn[3]};
    float4 fm;
    fm.x = xn[0] * (1.f + cb[scale_off + d + 0]) + cb[shift_off + d + 0];
    fm.y = xn[1] * (1.f + cb[scale_off + d + 1]) + cb[shift_off + d + 1];
    fm.z = xn[2] * (1.f + cb[scale_off + d + 2]) + cb[shift_off + d + 2];
    fm.w = xn[3] * (1.f + cb[scale_off + d + 3]) + cb[shift_off + d + 3];
    if (out_norm) *reinterpret_cast<float4*>(out_norm + base) = fn;
    if (out_mod)  *reinterpret_cast<float4*>(out_mod + base)  = fm;
    if (ws_mod) {
        ushort4 um = {f2b(fm.x), f2b(fm.y), f2b(fm.z), f2b(fm.w)};
        *reinterpret_cast<ushort4*>(ws_mod + base) = um;
    }
}

// ------------------------------------------------------------ MFMA GEMM
// C[M,N] = A[M,K] @ B[K,N] + bias; A,B bf16 (ws) row-major. 128x128 tile.
// MODE 0: Cb = bf16(C*alpha)                    (qkv)
// MODE 1: x1f = f32(Xres) + gate_msa * C        (attn proj + residual)
// MODE 2: Cb = bf16(gelu_exact(C))              (fc1)
// MODE 3: outf = x1f + gate_mlp * C             (fc2 + residual, f32 out)
template <int MODE>
__global__ __launch_bounds__(256, 2)
void gemm_kernel(const u16* __restrict__ A, const u16* __restrict__ B,
                 const void* __restrict__ bias, const int* __restrict__ flag,
                 int M, int N, int K, u16* __restrict__ Cb, float alpha,
                 const void* __restrict__ Xres, const float* __restrict__ cmodf,
                 int gate_off, float* __restrict__ x1f, float* __restrict__ outf) {
    __shared__ __align__(16) u16 Al[128 * 32];   // Al[m][k]
    __shared__ __align__(16) u16 Bl[128 * 32];   // Bl[n][k]  (transposed)
    const int tid = threadIdx.x;
    const int lane = tid & 63;
    const int wv = tid >> 6;
    const int m0 = blockIdx.y * 128;
    const int n0 = blockIdx.x * 128;
    const int wr = (wv & 1) * 64;
    const int wc = (wv >> 1) * 64;
    const int l15 = lane & 15;
    const int kq = (lane >> 4) << 3;
    f32x4 acc[4][4] = {};
    for (int k0 = 0; k0 < K; k0 += 32) {
        __syncthreads();
#pragma unroll
        for (int it = 0; it < 2; ++it) {
            int f = (it * 256 + tid) * 8;
            int am = f >> 5, ak = f & 31;
            *(bf16x8*)&Al[am * 32 + ak] =
                *(const bf16x8*)(A + (size_t)(m0 + am) * K + (k0 + ak));
            int bk = f >> 7, bn = f & 127;
            union { bf16x8 v; u16 u[8]; } t;
            t.v = *(const bf16x8*)(B + (size_t)(k0 + bk) * N + (n0 + bn));
#pragma unroll
            for (int e = 0; e < 8; ++e) Bl[(bn + e) * 32 + bk] = t.u[e];
        }
        __syncthreads();
        bf16x8 afr[4], bfr[4];
#pragma unroll
        for (int i = 0; i < 4; ++i)
            afr[i] = *(const bf16x8*)&Al[(wr + i * 16 + l15) * 32 + kq];
#pragma unroll
        for (int j = 0; j < 4; ++j)
            bfr[j] = *(const bf16x8*)&Bl[(wc + j * 16 + l15) * 32 + kq];
#pragma unroll
        for (int i = 0; i < 4; ++i)
#pragma unroll
            for (int j = 0; j < 4; ++j)
                acc[i][j] = __builtin_amdgcn_mfma_f32_16x16x32_bf16(
                    afr[i], bfr[j], acc[i][j], 0, 0, 0);
    }
    const int isf = flag[0];
    const int rbase = (lane >> 4) << 2;
#pragma unroll
    for (int i = 0; i < 4; ++i) {
#pragma unroll
        for (int j = 0; j < 4; ++j) {
            const int col = n0 + wc + j * 16 + l15;
            const float bv = isf ? ((const float*)bias)[col]
                                 : b2f(((const u16*)bias)[col]);
#pragma unroll
            for (int r = 0; r < 4; ++r) {
                const int m = m0 + wr + i * 16 + rbase + r;
                float t = acc[i][j][r] + bv;
                const size_t idx = (size_t)m * N + col;
                if (MODE == 0) {
                    Cb[idx] = f2b(t * alpha);
                } else if (MODE == 1) {
                    const int bb = m >> 10;
                    float g = cmodf[bb * 6144 + gate_off + col];
                    float xr = isf ? ((const float*)Xres)[idx]
                                   : b2f(((const u16*)Xres)[idx]);
                    x1f[idx] = xr + g * t;
                } else if (MODE == 2) {
                    float gl = 0.5f * t * (1.f + erff(t * 0.70710678118654752f));
                    Cb[idx] = f2b(gl);
                } else {
                    const int bb = m >> 10;
                    float g = cmodf[bb * 6144 + gate_off + col];
                    outf[idx] = x1f[idx] + g * t;
                }
            }
        }
    }
}

// --------------------------------------------- fused flash attention
__global__ __launch_bounds__(256)
void attn_kernel(const u16* __restrict__ Q, const u16* __restrict__ Kg,
                 const u16* __restrict__ Vg, u16* __restrict__ Y) {
    __shared__ __align__(16) u16 qT[16 * 64];     // [qi][c]
    __shared__ __align__(16) u16 kT[128 * 64];    // [kj][c]
    __shared__ __align__(16) u16 vT[64 * 128];    // [dh][kj]
    __shared__ __align__(16) float scT[16 * 128];
    __shared__ __align__(16) u16 pT[16 * 128];
    __shared__ float mBuf[16], lBuf[16], aBuf[16];
    const int tid = threadIdx.x;
    const int lane = tid & 63;
    const int wv = tid >> 6;
    const int l15 = lane & 15;
    const int kq = (lane >> 4) << 3;
    const int rbase = (lane >> 4) << 2;
    const int qt = blockIdx.x, h = blockIdx.y, b = blockIdx.z;
    const int s0 = qt * 16;
    const size_t hoff = (size_t)h * 64;
    if (tid < 16) { mBuf[tid] = -3e38f; lBuf[tid] = 0.f; }
    if (tid < 128) {
        int f = tid * 8;
        int qi = f >> 6, dd = f & 63;
        *(bf16x8*)&qT[qi * 64 + dd] =
            *(const bf16x8*)(Q + ((size_t)(b * 1024 + s0 + qi)) * 1024 + hoff + dd);
    }
    f32x4 accO = {0.f, 0.f, 0.f, 0.f};
    for (int kt = 0; kt < 8; ++kt) {
        __syncthreads();
#pragma unroll
        for (int it = 0; it < 4; ++it) {
            int f = (it * 256 + tid) * 8;
            int r = f >> 6, dd = f & 63;
            size_t gidx = ((size_t)(b * 1024 + kt * 128 + r)) * 1024 + hoff + dd;
            *(bf16x8*)&kT[r * 64 + dd] = *(const bf16x8*)(Kg + gidx);
            union { bf16x8 v; u16 u[8]; } t;
            t.v = *(const bf16x8*)(Vg + gidx);
#pragma unroll
            for (int e = 0; e < 8; ++e) vT[(dd + e) * 128 + r] = t.u[e];
        }
        __syncthreads();
#pragma unroll
        for (int t2 = 0; t2 < 2; ++t2) {
            const int nt = wv + t2 * 4;
            f32x4 s = {0.f, 0.f, 0.f, 0.f};
#pragma unroll
            for (int ks = 0; ks < 2; ++ks) {
                bf16x8 qa = *(const bf16x8*)&qT[l15 * 64 + ks * 32 + kq];
                bf16x8 kb = *(const bf16x8*)&kT[(nt * 16 + l15) * 64 + ks * 32 + kq];
                s = __builtin_amdgcn_mfma_f32_16x16x32_bf16(qa, kb, s, 0, 0, 0);
            }
#pragma unroll
            for (int r = 0; r < 4; ++r)
                scT[(rbase + r) * 128 + nt * 16 + l15] = s[r];
        }
        __syncthreads();
        for (int qi = wv; qi < 16; qi += 4) {
            float v0 = scT[qi * 128 + lane];
            float v1 = scT[qi * 128 + 64 + lane];
            float mx = fmaxf(v0, v1);
#pragma unroll
            for (int o = 32; o; o >>= 1) mx = fmaxf(mx, __shfl_xor(mx, o, 64));
            float mo = mBuf[qi];
            float mn = fmaxf(mo, mx);
            float al = __expf(mo - mn);
            float p0 = __expf(v0 - mn), p1 = __expf(v1 - mn);
            float sm = p0 + p1;
#pragma unroll
            for (int o = 32; o; o >>= 1) sm += __shfl_xor(sm, o, 64);
            pT[qi * 128 + lane] = f2b(p0);
            pT[qi * 128 + 64 + lane] = f2b(p1);
            if (lane == 0) { mBuf[qi] = mn; aBuf[qi] = al; lBuf[qi] = lBuf[qi] * al + sm; }
        }
        __syncthreads();
#pragma unroll
        for (int r = 0; r < 4; ++r) accO[r] *= aBuf[rbase + r];
#pragma unroll
        for (int ks = 0; ks < 4; ++ks) {
            bf16x8 pa = *(const bf16x8*)&pT[l15 * 128 + ks * 32 + kq];
            bf16x8 vb = *(const bf16x8*)&vT[(wv * 16 + l15) * 128 + ks * 32 + kq];
            accO = __builtin_amdgcn_mfma_f32_16x16x32_bf16(pa, vb, accO, 0, 0, 0);
        }
    }
#pragma unroll
    for (int r = 0; r < 4; ++r) {
        int row = rbase + r;
        float o = accO[r] / lBuf[row];
        Y[((size_t)(b * 1024 + s0 + row)) * 1024 + hoff + wv * 16 + l15] = f2b(o);
    }
}

// ----------------------------------------------------------------- launch
extern "C" void kernel_launch(void* const* d_in, const int* in_sizes, int n_in,
                              void* d_out, int out_size, void* d_ws, size_t ws_size,
                              hipStream_t stream) {
    const void* x      = d_in[0];
    const void* c      = d_in[1];
    const void* w_mod  = d_in[2];
    const void* b_mod  = d_in[3];
    const void* w_q    = d_in[4];
    const void* b_q    = d_in[5];
    const void* w_k    = d_in[6];
    const void* b_k    = d_in[7];
    const void* w_v    = d_in[8];
    const void* b_v    = d_in[9];
    const void* w_attn = d_in[10];
    const void* b_attn = d_in[11];
    const void* w_fc1  = d_in[12];
    const void* b_fc1  = d_in[13];
    const void* w_fc2  = d_in[14];
    const void* b_fc2  = d_in[15];

    float* out = (float*)d_out;
    float* out_xout  = out;                  // [8,1024,1024] f32
    float* out_norm  = out + 8388608;
    float* out_mod   = out + 16777216;
    float* out_shift = out + 25165824;
    float* out_scale = out + 25174016;
    float* out_cmod  = out + 25182208;
    float* out_cact  = out + 25231360;

    char* ws = (char*)d_ws;
    float* cactf = (float*)(ws + 0);            // 32 KB
    float* cmodf = (float*)(ws + 32768);        // 192 KB
    int*   flag  = (int*)(ws + 229376);         // 4 B
    u16* wqb  = (u16*)(ws + 1048576);           // 2 MB
    u16* wkb  = (u16*)(ws + 3145728);           // 2 MB
    u16* wvb  = (u16*)(ws + 5242880);           // 2 MB
    u16* wab  = (u16*)(ws + 7340032);           // 2 MB
    u16* wf1b = (u16*)(ws + 9437184);           // 8 MB
    u16* wf2b = (u16*)(ws + 17825792);          // 8 MB (end 25 MiB)
    u16* xmod  = (u16*)(ws + 26214400);         // 16 MB
    u16* qw    = (u16*)(ws + 42991616);         // 16 MB
    u16* kw    = (u16*)(ws + 59768832);         // 16 MB
    u16* vw    = (u16*)(ws + 76546048);         // 16 MB
    u16* yw    = xmod;                          // alias (xmod dead after v GEMM)
    float* x1f = (float*)(ws + 59768832);       // 32 MB alias kw+vw (dead after attn)
    u16* xmod2 = qw;                            // alias (qw dead after attn)
    u16* hw    = (u16*)(ws + 93323264);         // 64 MB (end ~153 MiB)

    sniff_kernel<<<1, 256, 0, stream>>>((const u16*)w_q, flag);
    cvt_kernel<<<512, 256, 0, stream>>>(w_q, wqb, 1048576, flag);
    cvt_kernel<<<512, 256, 0, stream>>>(w_k, wkb, 1048576, flag);
    cvt_kernel<<<512, 256, 0, stream>>>(w_v, wvb, 1048576, flag);
    cvt_kernel<<<512, 256, 0, stream>>>(w_attn, wab, 1048576, flag);
    cvt_kernel<<<2048, 256, 0, stream>>>(w_fc1, wf1b, 4194304, flag);
    cvt_kernel<<<2048, 256, 0, stream>>>(w_fc2, wf2b, 4194304, flag);

    silu_kernel<<<32, 256, 0, stream>>>(c, flag, cactf, out_cact);
    cmod_kernel<<<dim3(24, 8), 256, 0, stream>>>(cactf, w_mod, b_mod, flag, cmodf,
                                                 out_cmod, out_shift, out_scale);
    ln_mod_kernel<<<8192, 256, 0, stream>>>(x, flag, 0, cmodf, 0, 1024,
                                            out_norm, out_mod, xmod);
    gemm_kernel<0><<<dim3(8, 64), 256, 0, stream>>>(xmod, wqb, b_q, flag, 8192, 1024, 1024,
        qw, 1.f / 64.f, nullptr, nullptr, 0, nullptr, nullptr);
    gemm_kernel<0><<<dim3(8, 64), 256, 0, stream>>>(xmod, wkb, b_k, flag, 8192, 1024, 1024,
        kw, 1.f, nullptr, nullptr, 0, nullptr, nullptr);
    gemm_kernel<0><<<dim3(8, 64), 256, 0, stream>>>(xmod, wvb, b_v, flag, 8192, 1024, 1024,
        vw, 1.f, nullptr, nullptr, 0, nullptr, nullptr);
    attn_kernel<<<dim3(64, 16, 8), 256, 0, stream>>>(qw, kw, vw, yw);
    gemm_kernel<1><<<dim3(8, 64), 256, 0, stream>>>(yw, wab, b_attn, flag, 8192, 1024, 1024,
        nullptr, 1.f, x, cmodf, 2048, x1f, nullptr);
    ln_mod_kernel<<<8192, 256, 0, stream>>>(x1f, flag, 1, cmodf, 3072, 4096,
                                            nullptr, nullptr, xmod2);
    gemm_kernel<2><<<dim3(32, 64), 256, 0, stream>>>(xmod2, wf1b, b_fc1, flag, 8192, 4096, 1024,
        hw, 1.f, nullptr, nullptr, 0, nullptr, nullptr);
    gemm_kernel<3><<<dim3(8, 64), 256, 0, stream>>>(hw, wf2b, b_fc2, flag, 8192, 1024, 4096,
        nullptr, 1.f, nullptr, cmodf, 5120, x1f, out_xout);

    (void)in_sizes; (void)n_in; (void)out_size; (void)ws_size;
}

// Round 4
// 865.333 us; speedup vs baseline: 2.1644x; 2.1644x over previous
//
#include <hip/hip_runtime.h>
#include <math.h>

typedef unsigned short u16;
typedef __bf16 bf16;
typedef bf16 bf16x8 __attribute__((ext_vector_type(8)));
typedef float f32x4 __attribute__((ext_vector_type(4)));

__device__ __forceinline__ float b2f(u16 u) {
    union { unsigned int i; float f; } w;
    w.i = ((unsigned int)u) << 16;
    return w.f;
}
__device__ __forceinline__ u16 f2b(float f) {
    union { float f; unsigned int i; } w;
    w.f = f;
    unsigned int x = w.i;
    return (u16)((x + 0x7fffu + ((x >> 16) & 1u)) >> 16);
}
__device__ __forceinline__ void gload16(const void* g, void* l) {
    __builtin_amdgcn_global_load_lds(
        (const __attribute__((address_space(1))) unsigned int*)g,
        (__attribute__((address_space(3))) unsigned int*)l, 16, 0, 0);
}

// ---------------------------------------------------------- input dtype sniff
__global__ __launch_bounds__(256)
void sniff_kernel(const u16* __restrict__ w, int* __restrict__ flag) {
    __shared__ int s;
    if (threadIdx.x == 0) s = 0;
    __syncthreads();
    int big = 0;
    for (int i = threadIdx.x; i < 2048; i += 256) {
        float v = fabsf(b2f(w[2 * i]));
        if (!(v < 1e6f)) big = 1;
    }
    if (big) atomicOr(&s, 1);
    __syncthreads();
    if (threadIdx.x == 0) flag[0] = s;
}

// ------------------------------------------- weight transpose W[K][N]->WT[N][K] bf16
__global__ __launch_bounds__(256)
void transpose_w_kernel(const void* __restrict__ W, const int* __restrict__ flag,
                        int K, int N, u16* __restrict__ out, int rowoff,
                        int ldout, float scale) {
    __shared__ float T[32][33];
    const int tx = threadIdx.x & 31, ty = threadIdx.x >> 5;   // 32 x 8
    const int kt = blockIdx.y * 32, nt = blockIdx.x * 32;
    const int isf = flag[0];
#pragma unroll
    for (int r = 0; r < 4; ++r) {
        int k = kt + ty + r * 8;
        float v = isf ? ((const float*)W)[(size_t)k * N + nt + tx]
                      : b2f(((const u16*)W)[(size_t)k * N + nt + tx]);
        T[ty + r * 8][tx] = v;
    }
    __syncthreads();
#pragma unroll
    for (int r = 0; r < 4; ++r) {
        int n = nt + ty + r * 8;
        out[(size_t)(rowoff + n) * ldout + kt + tx] = f2b(T[tx][ty + r * 8] * scale);
    }
}

// ------------------------------------------- concat qkv bias (q scaled 1/64)
__global__ __launch_bounds__(256)
void biasqkv_kernel(const void* __restrict__ bq, const void* __restrict__ bk,
                    const void* __restrict__ bv, const int* __restrict__ flag,
                    float* __restrict__ out) {
    int i = blockIdx.x * 256 + threadIdx.x;
    if (i >= 3072) return;
    const int isf = flag[0];
    const void* src = i < 1024 ? bq : (i < 2048 ? bk : bv);
    int j = i & 1023;
    float v = isf ? ((const float*)src)[j] : b2f(((const u16*)src)[j]);
    if (i < 1024) v *= (1.f / 64.f);
    out[i] = v;
}

// ---------------------------------------------------------------- silu(c)
__global__ __launch_bounds__(256)
void silu_kernel(const void* __restrict__ c, const int* __restrict__ flag,
                 float* __restrict__ cactf, float* __restrict__ out_cact) {
    int i = blockIdx.x * 256 + threadIdx.x;
    if (i < 8 * 1024) {
        float v = flag[0] ? ((const float*)c)[i] : b2f(((const u16*)c)[i]);
        float s = v / (1.f + expf(-v));
        cactf[i] = s;
        out_cact[i] = s;
    }
}

// ------------------------------------------- cmod = silu(c) @ w_mod + b_mod
// grid 24 x 256 threads; each thread one col j, all 8 batches; cact in LDS.
__global__ __launch_bounds__(256)
void cmod_kernel(const float* __restrict__ cactf, const void* __restrict__ w_mod,
                 const void* __restrict__ b_mod, const int* __restrict__ flag,
                 float* __restrict__ cmodf, float* __restrict__ out_cmod,
                 float* __restrict__ out_shift, float* __restrict__ out_scale) {
    __shared__ float sca[8192];
    const int tid = threadIdx.x;
    for (int i = tid; i < 8192; i += 256) sca[i] = cactf[i];
    __syncthreads();
    const int j = blockIdx.x * 256 + tid;
    const int isf = flag[0];
    float bm = isf ? ((const float*)b_mod)[j] : b2f(((const u16*)b_mod)[j]);
    float acc[8];
#pragma unroll
    for (int b = 0; b < 8; ++b) acc[b] = bm;
    if (isf) {
        const float* wf = (const float*)w_mod;
        for (int k = 0; k < 1024; ++k) {
            float wv = wf[(size_t)k * 6144 + j];
#pragma unroll
            for (int b = 0; b < 8; ++b) acc[b] = fmaf(sca[b * 1024 + k], wv, acc[b]);
        }
    } else {
        const u16* wb = (const u16*)w_mod;
        for (int k = 0; k < 1024; ++k) {
            float wv = b2f(wb[(size_t)k * 6144 + j]);
#pragma unroll
            for (int b = 0; b < 8; ++b) acc[b] = fmaf(sca[b * 1024 + k], wv, acc[b]);
        }
    }
#pragma unroll
    for (int b = 0; b < 8; ++b) {
        float v = acc[b];
        cmodf[b * 6144 + j] = v;
        out_cmod[b * 6144 + j] = v;
        if (j < 1024) out_shift[b * 1024 + j] = v;
        else if (j < 2048) out_scale[b * 1024 + (j - 1024)] = v;
    }
}

// -------------------------------------------------- LayerNorm + modulate
// dtype: 0 = bf16 input, 1 = f32 input, 2 = per flag
__global__ __launch_bounds__(256)
void ln_mod_kernel(const void* __restrict__ xin, const int* __restrict__ flag,
                   int dtype, const float* __restrict__ cmodf,
                   int shift_off, int scale_off, float* __restrict__ out_norm,
                   float* __restrict__ out_mod, u16* __restrict__ ws_mod) {
    const int row = blockIdx.x;
    const int tid = threadIdx.x;
    const int bidx = row >> 10;
    const int isf = (dtype == 2) ? flag[0] : dtype;
    const size_t base = (size_t)row * 1024 + tid * 4;
    float v[4];
    if (isf) {
        float4 f = *reinterpret_cast<const float4*>((const float*)xin + base);
        v[0] = f.x; v[1] = f.y; v[2] = f.z; v[3] = f.w;
    } else {
        ushort4 u = *reinterpret_cast<const ushort4*>((const u16*)xin + base);
        v[0] = b2f(u.x); v[1] = b2f(u.y); v[2] = b2f(u.z); v[3] = b2f(u.w);
    }
    float s = v[0] + v[1] + v[2] + v[3];
#pragma unroll
    for (int o = 32; o; o >>= 1) s += __shfl_xor(s, o, 64);
    __shared__ float red1[4], red2[4];
    const int lane = tid & 63, wv = tid >> 6;
    if (lane == 0) red1[wv] = s;
    __syncthreads();
    float mean = (red1[0] + red1[1] + red1[2] + red1[3]) * 0.0009765625f;
    float d0 = v[0] - mean, d1 = v[1] - mean, d2 = v[2] - mean, d3 = v[3] - mean;
    float sq = d0 * d0 + d1 * d1 + d2 * d2 + d3 * d3;
#pragma unroll
    for (int o = 32; o; o >>= 1) sq += __shfl_xor(sq, o, 64);
    if (lane == 0) red2[wv] = sq;
    __syncthreads();
    float var = (red2[0] + red2[1] + red2[2] + red2[3]) * 0.0009765625f;
    float rs = rsqrtf(var + 1e-6f);
    float xn[4] = {d0 * rs, d1 * rs, d2 * rs, d3 * rs};
    const int d = tid * 4;
    const float* cb = cmodf + bidx * 6144;
    float4 fn = {xn[0], xn[1], xn[2], xn[3]};
    float4 fm;
    fm.x = xn[0] * (1.f + cb[scale_off + d + 0]) + cb[shift_off + d + 0];
    fm.y = xn[1] * (1.f + cb[scale_off + d + 1]) + cb[shift_off + d + 1];
    fm.z = xn[2] * (1.f + cb[scale_off + d + 2]) + cb[shift_off + d + 2];
    fm.w = xn[3] * (1.f + cb[scale_off + d + 3]) + cb[shift_off + d + 3];
    if (out_norm) *reinterpret_cast<float4*>(out_norm + base) = fn;
    if (out_mod)  *reinterpret_cast<float4*>(out_mod + base)  = fm;
    if (ws_mod) {
        ushort4 um = {f2b(fm.x), f2b(fm.y), f2b(fm.z), f2b(fm.w)};
        *reinterpret_cast<ushort4*>(ws_mod + base) = um;
    }
}

// ------------------------------------------------------------ MFMA GEMM (m97)
// C[M,N] = A[M,K] @ BT[N,K]^T + bias; 128x128 tile, global_load_lds staging.
// MODE 0: Cb = bf16(C + bias32)                 (fused qkv, ld N)
// MODE 1: x1b = bf16(f(Xres) + gate_msa * C)    (attn proj + residual)
// MODE 2: Cb = bf16(gelu_exact(C))              (fc1)
// MODE 3: outf = f(x1b) + gate_mlp * C          (fc2 + residual, f32 out)
template <int MODE>
__global__ __launch_bounds__(256, 2)
void gemm_kernel(const u16* __restrict__ A, const u16* __restrict__ BT,
                 const void* __restrict__ bias, const float* __restrict__ bias32,
                 const int* __restrict__ flag, int M, int N, int K,
                 u16* __restrict__ Cb, const void* __restrict__ Xres,
                 const float* __restrict__ cmodf, int gate_off,
                 u16* __restrict__ x1b, float* __restrict__ outf) {
    __shared__ __align__(16) u16 Al[128 * 32];   // [m][k] contiguous
    __shared__ __align__(16) u16 Bl[128 * 32];   // [n][k] contiguous
    const int tid = threadIdx.x, lane = tid & 63, w = tid >> 6;
    const int m0 = blockIdx.y * 128, n0 = blockIdx.x * 128;
    const int wr = (w & 1) * 64, wc = (w >> 1) * 64;
    const int l15 = lane & 15, kq = (lane >> 4) << 3;
    const int srow = lane >> 2, skoff = (lane & 3) * 8;
    f32x4 acc[4][4] = {};
    for (int k0 = 0; k0 < K; k0 += 32) {
        __syncthreads();
#pragma unroll
        for (int c = 0; c < 2; ++c) {
            const int chunk = w * 2 + c;
            const int row = chunk * 16 + srow;
            gload16(A + (size_t)(m0 + row) * K + k0 + skoff, &Al[chunk * 512]);
            gload16(BT + (size_t)(n0 + row) * K + k0 + skoff, &Bl[chunk * 512]);
        }
        __syncthreads();
        bf16x8 afr[4], bfr[4];
#pragma unroll
        for (int i = 0; i < 4; ++i)
            afr[i] = *(const bf16x8*)&Al[(wr + i * 16 + l15) * 32 + kq];
#pragma unroll
        for (int j = 0; j < 4; ++j)
            bfr[j] = *(const bf16x8*)&Bl[(wc + j * 16 + l15) * 32 + kq];
#pragma unroll
        for (int i = 0; i < 4; ++i)
#pragma unroll
            for (int j = 0; j < 4; ++j)
                acc[i][j] = __builtin_amdgcn_mfma_f32_16x16x32_bf16(
                    afr[i], bfr[j], acc[i][j], 0, 0, 0);
    }
    const int isf = flag[0];
    const int rbase = (lane >> 4) << 2;
#pragma unroll
    for (int i = 0; i < 4; ++i) {
#pragma unroll
        for (int j = 0; j < 4; ++j) {
            const int col = n0 + wc + j * 16 + l15;
            float bv;
            if (MODE == 0) bv = bias32[col];
            else bv = isf ? ((const float*)bias)[col] : b2f(((const u16*)bias)[col]);
#pragma unroll
            for (int r = 0; r < 4; ++r) {
                const int m = m0 + wr + i * 16 + rbase + r;
                float t = acc[i][j][r] + bv;
                const size_t idx = (size_t)m * N + col;
                if (MODE == 0) {
                    Cb[idx] = f2b(t);
                } else if (MODE == 1) {
                    const int bb = m >> 10;
                    float g = cmodf[bb * 6144 + gate_off + col];
                    float xr = isf ? ((const float*)Xres)[idx]
                                   : b2f(((const u16*)Xres)[idx]);
                    x1b[idx] = f2b(xr + g * t);
                } else if (MODE == 2) {
                    float gl = 0.5f * t * (1.f + erff(t * 0.70710678118654752f));
                    Cb[idx] = f2b(gl);
                } else {
                    const int bb = m >> 10;
                    float g = cmodf[bb * 6144 + gate_off + col];
                    outf[idx] = b2f(x1b[idx]) + g * t;
                }
            }
        }
    }
}

// --------------------------------------------- fused flash attention (64-row Q)
// Grid (16,16,8), 256 thr. QKV fused buffer [8192][3072]: Q+0,K+1024,V+2048.
// Register online-softmax; padded LDS (72/136) => ~conflict-free.
__global__ __launch_bounds__(256)
void attn_kernel(const u16* __restrict__ QKV, u16* __restrict__ Y) {
    __shared__ __align__(16) u16 qS[64 * 72];
    __shared__ __align__(16) u16 kS[128 * 72];
    __shared__ __align__(16) u16 vT[64 * 136];   // [dh][key]
    __shared__ __align__(16) u16 pT[64 * 136];   // [q][key]
    const int tid = threadIdx.x, lane = tid & 63, w = tid >> 6;
    const int l15 = lane & 15, quad = lane >> 4;
    const int kq = quad * 8, rbase = quad * 4;
    const int qt = blockIdx.x, h = blockIdx.y, b = blockIdx.z;
    const int s0 = qt * 64;
    const size_t rowbase = (size_t)b * 1024;
    const int hoff = h * 64;
#pragma unroll
    for (int it = 0; it < 2; ++it) {
        int idx = it * 256 + tid;          // 512 chunks of 8 u16
        int r = idx >> 3, ch = idx & 7;
        *(bf16x8*)&qS[r * 72 + ch * 8] =
            *(const bf16x8*)(QKV + (rowbase + s0 + r) * 3072 + hoff + ch * 8);
    }
    f32x4 accO[4] = {};
    float m_i[4], l_i[4];
#pragma unroll
    for (int r = 0; r < 4; ++r) { m_i[r] = -3e38f; l_i[r] = 0.f; }
    for (int kt = 0; kt < 8; ++kt) {
        __syncthreads();                    // prev tile fully consumed
#pragma unroll
        for (int it = 0; it < 4; ++it) {    // K tile 128x64
            int idx = it * 256 + tid;
            int r = idx >> 3, ch = idx & 7;
            *(bf16x8*)&kS[r * 72 + ch * 8] =
                *(const bf16x8*)(QKV + (rowbase + kt * 128 + r) * 3072 + 1024 + hoff + ch * 8);
        }
#pragma unroll
        for (int j2 = 0; j2 < 4; ++j2) {    // V^T: wave w keys [w*32, w*32+32)
            int kbase = w * 32 + j2 * 8;
            union { bf16x8 v; u16 u[8]; } t;
#pragma unroll
            for (int jj = 0; jj < 8; ++jj)
                t.u[jj] = QKV[(rowbase + kt * 128 + kbase + jj) * 3072 + 2048 + hoff + lane];
            *(bf16x8*)&vT[lane * 136 + kbase] = t.v;
        }
        __syncthreads();
        // S = Q K^T : wave rows w*16.., 8 key-tiles
        f32x4 s[8];
#pragma unroll
        for (int nt = 0; nt < 8; ++nt) {
            f32x4 a = {};
#pragma unroll
            for (int ks = 0; ks < 2; ++ks) {
                bf16x8 qa = *(const bf16x8*)&qS[(w * 16 + l15) * 72 + ks * 32 + kq];
                bf16x8 kb = *(const bf16x8*)&kS[(nt * 16 + l15) * 72 + ks * 32 + kq];
                a = __builtin_amdgcn_mfma_f32_16x16x32_bf16(qa, kb, a, 0, 0, 0);
            }
            s[nt] = a;
        }
        float alpha[4];
#pragma unroll
        for (int r = 0; r < 4; ++r) {
            float mx = s[0][r];
#pragma unroll
            for (int nt = 1; nt < 8; ++nt) mx = fmaxf(mx, s[nt][r]);
            mx = fmaxf(mx, __shfl_xor(mx, 1));
            mx = fmaxf(mx, __shfl_xor(mx, 2));
            mx = fmaxf(mx, __shfl_xor(mx, 4));
            mx = fmaxf(mx, __shfl_xor(mx, 8));
            float mn = fmaxf(m_i[r], mx);
            alpha[r] = __expf(m_i[r] - mn);
            m_i[r] = mn;
            float rs = 0.f;
#pragma unroll
            for (int nt = 0; nt < 8; ++nt) {
                float p = __expf(s[nt][r] - mn);
                s[nt][r] = p;
                rs += p;
            }
            rs += __shfl_xor(rs, 1);
            rs += __shfl_xor(rs, 2);
            rs += __shfl_xor(rs, 4);
            rs += __shfl_xor(rs, 8);
            l_i[r] = l_i[r] * alpha[r] + rs;
        }
        // P -> LDS (paired u32 stores, even l15 lanes)
#pragma unroll
        for (int nt = 0; nt < 8; ++nt) {
#pragma unroll
            for (int r = 0; r < 4; ++r) {
                float v = s[nt][r];
                float vo = __shfl_xor(v, 1);
                if ((l15 & 1) == 0) {
                    unsigned int pk = (unsigned int)f2b(v) | ((unsigned int)f2b(vo) << 16);
                    ((unsigned int*)pT)[(w * 16 + rbase + r) * 68 + nt * 8 + (l15 >> 1)] = pk;
                }
            }
        }
        __syncthreads();
#pragma unroll
        for (int dt = 0; dt < 4; ++dt)
#pragma unroll
            for (int r = 0; r < 4; ++r) accO[dt][r] *= alpha[r];
#pragma unroll
        for (int dt = 0; dt < 4; ++dt) {
#pragma unroll
            for (int ks = 0; ks < 4; ++ks) {
                bf16x8 pa = *(const bf16x8*)&pT[(w * 16 + l15) * 136 + ks * 32 + kq];
                bf16x8 vb = *(const bf16x8*)&vT[(dt * 16 + l15) * 136 + ks * 32 + kq];
                accO[dt] = __builtin_amdgcn_mfma_f32_16x16x32_bf16(pa, vb, accO[dt], 0, 0, 0);
            }
        }
    }
#pragma unroll
    for (int dt = 0; dt < 4; ++dt)
#pragma unroll
        for (int r = 0; r < 4; ++r) {
            float o = accO[dt][r] / l_i[r];
            Y[(rowbase + s0 + w * 16 + rbase + r) * 1024 + hoff + dt * 16 + l15] = f2b(o);
        }
}

// ----------------------------------------------------------------- launch
extern "C" void kernel_launch(void* const* d_in, const int* in_sizes, int n_in,
                              void* d_out, int out_size, void* d_ws, size_t ws_size,
                              hipStream_t stream) {
    const void* x      = d_in[0];
    const void* c      = d_in[1];
    const void* w_mod  = d_in[2];
    const void* b_mod  = d_in[3];
    const void* w_q    = d_in[4];
    const void* b_q    = d_in[5];
    const void* w_k    = d_in[6];
    const void* b_k    = d_in[7];
    const void* w_v    = d_in[8];
    const void* b_v    = d_in[9];
    const void* w_attn = d_in[10];
    const void* b_attn = d_in[11];
    const void* w_fc1  = d_in[12];
    const void* b_fc1  = d_in[13];
    const void* w_fc2  = d_in[14];
    const void* b_fc2  = d_in[15];

    float* out = (float*)d_out;
    float* out_xout  = out;
    float* out_norm  = out + 8388608;
    float* out_mod   = out + 16777216;
    float* out_shift = out + 25165824;
    float* out_scale = out + 25174016;
    float* out_cmod  = out + 25182208;
    float* out_cact  = out + 25231360;

    char* ws = (char*)d_ws;
    float* cactf  = (float*)(ws + 0);           // 32 KB
    float* cmodf  = (float*)(ws + 32768);       // 192 KB
    int*   flag   = (int*)(ws + 229376);
    float* bqkv   = (float*)(ws + 230400);      // 12 KB
    u16* wqkvT = (u16*)(ws + 1048576);          // [3072][1024] 6 MB
    u16* waT   = (u16*)(ws + 7340032);          // [1024][1024] 2 MB
    u16* wf1T  = (u16*)(ws + 9437184);          // [4096][1024] 8 MB
    u16* wf2T  = (u16*)(ws + 17825792);         // [1024][4096] 8 MB
    u16* xmod  = (u16*)(ws + 26214400);         // 16 MB
    u16* yw    = xmod;                          // alias: xmod dead after qkv GEMM
    u16* qkv   = (u16*)(ws + 42991616);         // [8192][3072] 48 MB
    u16* xmod2 = qkv;                           // alias: qkv dead after attn
    u16* hw    = (u16*)(ws + 59768832);         // [8192][4096] 64 MB
    u16* x1b   = (u16*)(ws + 126877696);        // 16 MB (end ~137 MiB)

    sniff_kernel<<<1, 256, 0, stream>>>((const u16*)w_q, flag);
    transpose_w_kernel<<<dim3(32, 32), 256, 0, stream>>>(w_q, flag, 1024, 1024,
        wqkvT, 0, 1024, 1.f / 64.f);
    transpose_w_kernel<<<dim3(32, 32), 256, 0, stream>>>(w_k, flag, 1024, 1024,
        wqkvT, 1024, 1024, 1.f);
    transpose_w_kernel<<<dim3(32, 32), 256, 0, stream>>>(w_v, flag, 1024, 1024,
        wqkvT, 2048, 1024, 1.f);
    transpose_w_kernel<<<dim3(32, 32), 256, 0, stream>>>(w_attn, flag, 1024, 1024,
        waT, 0, 1024, 1.f);
    transpose_w_kernel<<<dim3(128, 32), 256, 0, stream>>>(w_fc1, flag, 1024, 4096,
        wf1T, 0, 1024, 1.f);
    transpose_w_kernel<<<dim3(32, 128), 256, 0, stream>>>(w_fc2, flag, 4096, 1024,
        wf2T, 0, 4096, 1.f);
    biasqkv_kernel<<<12, 256, 0, stream>>>(b_q, b_k, b_v, flag, bqkv);

    silu_kernel<<<32, 256, 0, stream>>>(c, flag, cactf, out_cact);
    cmod_kernel<<<24, 256, 0, stream>>>(cactf, w_mod, b_mod, flag, cmodf,
                                        out_cmod, out_shift, out_scale);
    ln_mod_kernel<<<8192, 256, 0, stream>>>(x, flag, 2, cmodf, 0, 1024,
                                            out_norm, out_mod, xmod);
    gemm_kernel<0><<<dim3(24, 64), 256, 0, stream>>>(xmod, wqkvT, nullptr, bqkv,
        flag, 8192, 3072, 1024, qkv, nullptr, nullptr, 0, nullptr, nullptr);
    attn_kernel<<<dim3(16, 16, 8), 256, 0, stream>>>(qkv, yw);
    gemm_kernel<1><<<dim3(8, 64), 256, 0, stream>>>(yw, waT, b_attn, nullptr,
        flag, 8192, 1024, 1024, nullptr, x, cmodf, 2048, x1b, nullptr);
    ln_mod_kernel<<<8192, 256, 0, stream>>>(x1b, flag, 0, cmodf, 3072, 4096,
                                            nullptr, nullptr, xmod2);
    gemm_kernel<2><<<dim3(32, 64), 256, 0, stream>>>(xmod2, wf1T, b_fc1, nullptr,
        flag, 8192, 4096, 1024, hw, nullptr, nullptr, 0, nullptr, nullptr);
    gemm_kernel<3><<<dim3(8, 64), 256, 0, stream>>>(hw, wf2T, b_fc2, nullptr,
        flag, 8192, 1024, 4096, nullptr, nullptr, cmodf, 5120, x1b, out_xout);

    (void)in_sizes; (void)n_in; (void)out_size; (void)ws_size;
}

// Round 5
// 734.022 us; speedup vs baseline: 2.5516x; 1.1789x over previous
//
#include <hip/hip_runtime.h>
#include <math.h>

typedef unsigned short u16;
typedef __bf16 bf16;
typedef bf16 bf16x8 __attribute__((ext_vector_type(8)));
typedef float f32x4 __attribute__((ext_vector_type(4)));

__device__ __forceinline__ float b2f(u16 u) {
    union { unsigned int i; float f; } w;
    w.i = ((unsigned int)u) << 16;
    return w.f;
}
__device__ __forceinline__ u16 f2b(float f) {
    union { float f; unsigned int i; } w;
    w.f = f;
    unsigned int x = w.i;
    return (u16)((x + 0x7fffu + ((x >> 16) & 1u)) >> 16);
}
__device__ __forceinline__ void gload16(const void* g, void* l) {
    __builtin_amdgcn_global_load_lds(
        (const __attribute__((address_space(1))) unsigned int*)g,
        (__attribute__((address_space(3))) unsigned int*)l, 16, 0, 0);
}

// ---------------------------------------------------------- input dtype sniff
__global__ __launch_bounds__(256)
void sniff_kernel(const u16* __restrict__ w, int* __restrict__ flag) {
    __shared__ int s;
    if (threadIdx.x == 0) s = 0;
    __syncthreads();
    int big = 0;
    for (int i = threadIdx.x; i < 2048; i += 256) {
        float v = fabsf(b2f(w[2 * i]));
        if (!(v < 1e6f)) big = 1;
    }
    if (big) atomicOr(&s, 1);
    __syncthreads();
    if (threadIdx.x == 0) flag[0] = s;
}

// --------------------- 4x square weight transpose W[1024][1024]->WT (one launch)
__global__ __launch_bounds__(256)
void transpose_w4_kernel(const void* __restrict__ W0, const void* __restrict__ W1,
                         const void* __restrict__ W2, const void* __restrict__ W3,
                         const int* __restrict__ flag, u16* __restrict__ oQKV,
                         u16* __restrict__ oA) {
    __shared__ float T[32][33];
    const int z = blockIdx.z;
    const void* W = z == 0 ? W0 : (z == 1 ? W1 : (z == 2 ? W2 : W3));
    u16* out = z == 3 ? oA : (oQKV + (size_t)z * 1024 * 1024);
    const float scale = z == 0 ? (1.f / 64.f) : 1.f;
    const int tx = threadIdx.x & 31, ty = threadIdx.x >> 5;   // 32 x 8
    const int kt = blockIdx.y * 32, nt = blockIdx.x * 32;
    const int isf = flag[0];
#pragma unroll
    for (int r = 0; r < 4; ++r) {
        int k = kt + ty + r * 8;
        float v = isf ? ((const float*)W)[(size_t)k * 1024 + nt + tx]
                      : b2f(((const u16*)W)[(size_t)k * 1024 + nt + tx]);
        T[ty + r * 8][tx] = v;
    }
    __syncthreads();
#pragma unroll
    for (int r = 0; r < 4; ++r) {
        int n = nt + ty + r * 8;
        out[(size_t)n * 1024 + kt + tx] = f2b(T[tx][ty + r * 8] * scale);
    }
}

// ------------------------------------------- generic transpose (fc1/fc2)
__global__ __launch_bounds__(256)
void transpose_w_kernel(const void* __restrict__ W, const int* __restrict__ flag,
                        int K, int N, u16* __restrict__ out) {
    __shared__ float T[32][33];
    const int tx = threadIdx.x & 31, ty = threadIdx.x >> 5;
    const int kt = blockIdx.y * 32, nt = blockIdx.x * 32;
    const int isf = flag[0];
#pragma unroll
    for (int r = 0; r < 4; ++r) {
        int k = kt + ty + r * 8;
        float v = isf ? ((const float*)W)[(size_t)k * N + nt + tx]
                      : b2f(((const u16*)W)[(size_t)k * N + nt + tx]);
        T[ty + r * 8][tx] = v;
    }
    __syncthreads();
#pragma unroll
    for (int r = 0; r < 4; ++r) {
        int n = nt + ty + r * 8;
        out[(size_t)n * K + kt + tx] = f2b(T[tx][ty + r * 8]);
    }
}

// ------------------------------------------- concat qkv bias (q scaled 1/64)
__global__ __launch_bounds__(256)
void biasqkv_kernel(const void* __restrict__ bq, const void* __restrict__ bk,
                    const void* __restrict__ bv, const int* __restrict__ flag,
                    float* __restrict__ out) {
    int i = blockIdx.x * 256 + threadIdx.x;
    if (i >= 3072) return;
    const int isf = flag[0];
    const void* src = i < 1024 ? bq : (i < 2048 ? bk : bv);
    int j = i & 1023;
    float v = isf ? ((const float*)src)[j] : b2f(((const u16*)src)[j]);
    if (i < 1024) v *= (1.f / 64.f);
    out[i] = v;
}

// ---------------------------------------------------------------- silu(c)
__global__ __launch_bounds__(256)
void silu_kernel(const void* __restrict__ c, const int* __restrict__ flag,
                 float* __restrict__ cactf, float* __restrict__ out_cact) {
    int i = blockIdx.x * 256 + threadIdx.x;
    if (i < 8 * 1024) {
        float v = flag[0] ? ((const float*)c)[i] : b2f(((const u16*)c)[i]);
        float s = v / (1.f + expf(-v));
        cactf[i] = s;
        out_cact[i] = s;
    }
}

// ---------------------------- cmod stage 1: partial[ks][b][j] over 128 k's
__global__ __launch_bounds__(256)
void cmod1_kernel(const float* __restrict__ cactf, const void* __restrict__ w_mod,
                  const int* __restrict__ flag, float* __restrict__ partial) {
    __shared__ float sca[8][128];
    const int tid = threadIdx.x;
    const int ks = blockIdx.y;
    if (tid < 128) {
#pragma unroll
        for (int b = 0; b < 8; ++b) sca[b][tid] = cactf[b * 1024 + ks * 128 + tid];
    }
    __syncthreads();
    const int j = blockIdx.x * 256 + tid;
    const int isf = flag[0];
    float acc[8] = {};
    if (isf) {
        const float* wf = (const float*)w_mod + (size_t)(ks * 128) * 6144 + j;
        for (int k = 0; k < 128; ++k) {
            float wv = wf[(size_t)k * 6144];
#pragma unroll
            for (int b = 0; b < 8; ++b) acc[b] = fmaf(sca[b][k], wv, acc[b]);
        }
    } else {
        const u16* wb = (const u16*)w_mod + (size_t)(ks * 128) * 6144 + j;
        for (int k = 0; k < 128; ++k) {
            float wv = b2f(wb[(size_t)k * 6144]);
#pragma unroll
            for (int b = 0; b < 8; ++b) acc[b] = fmaf(sca[b][k], wv, acc[b]);
        }
    }
#pragma unroll
    for (int b = 0; b < 8; ++b) partial[(ks * 8 + b) * 6144 + j] = acc[b];
}

// ---------------------------- cmod stage 2: reduce + bias + outputs
__global__ __launch_bounds__(256)
void cmod2_kernel(const float* __restrict__ partial, const void* __restrict__ b_mod,
                  const int* __restrict__ flag, float* __restrict__ cmodf,
                  float* __restrict__ out_cmod, float* __restrict__ out_shift,
                  float* __restrict__ out_scale) {
    const int j = blockIdx.x * 256 + threadIdx.x;
    const int isf = flag[0];
    float bm = isf ? ((const float*)b_mod)[j] : b2f(((const u16*)b_mod)[j]);
#pragma unroll
    for (int b = 0; b < 8; ++b) {
        float acc = bm;
#pragma unroll
        for (int ks = 0; ks < 8; ++ks) acc += partial[(ks * 8 + b) * 6144 + j];
        cmodf[b * 6144 + j] = acc;
        out_cmod[b * 6144 + j] = acc;
        if (j < 1024) out_shift[b * 1024 + j] = acc;
        else if (j < 2048) out_scale[b * 1024 + (j - 1024)] = acc;
    }
}

// -------------------------------------------------- LayerNorm + modulate
__global__ __launch_bounds__(256)
void ln_mod_kernel(const void* __restrict__ xin, const int* __restrict__ flag,
                   int dtype, const float* __restrict__ cmodf,
                   int shift_off, int scale_off, float* __restrict__ out_norm,
                   float* __restrict__ out_mod, u16* __restrict__ ws_mod) {
    const int row = blockIdx.x;
    const int tid = threadIdx.x;
    const int bidx = row >> 10;
    const int isf = (dtype == 2) ? flag[0] : dtype;
    const size_t base = (size_t)row * 1024 + tid * 4;
    float v[4];
    if (isf) {
        float4 f = *reinterpret_cast<const float4*>((const float*)xin + base);
        v[0] = f.x; v[1] = f.y; v[2] = f.z; v[3] = f.w;
    } else {
        ushort4 u = *reinterpret_cast<const ushort4*>((const u16*)xin + base);
        v[0] = b2f(u.x); v[1] = b2f(u.y); v[2] = b2f(u.z); v[3] = b2f(u.w);
    }
    float s = v[0] + v[1] + v[2] + v[3];
#pragma unroll
    for (int o = 32; o; o >>= 1) s += __shfl_xor(s, o, 64);
    __shared__ float red1[4], red2[4];
    const int lane = tid & 63, wv = tid >> 6;
    if (lane == 0) red1[wv] = s;
    __syncthreads();
    float mean = (red1[0] + red1[1] + red1[2] + red1[3]) * 0.0009765625f;
    float d0 = v[0] - mean, d1 = v[1] - mean, d2 = v[2] - mean, d3 = v[3] - mean;
    float sq = d0 * d0 + d1 * d1 + d2 * d2 + d3 * d3;
#pragma unroll
    for (int o = 32; o; o >>= 1) sq += __shfl_xor(sq, o, 64);
    if (lane == 0) red2[wv] = sq;
    __syncthreads();
    float var = (red2[0] + red2[1] + red2[2] + red2[3]) * 0.0009765625f;
    float rs = rsqrtf(var + 1e-6f);
    float xn[4] = {d0 * rs, d1 * rs, d2 * rs, d3 * rs};
    const int d = tid * 4;
    const float* cb = cmodf + bidx * 6144;
    float4 fn = {xn[0], xn[1], xn[2], xn[3]};
    float4 fm;
    fm.x = xn[0] * (1.f + cb[scale_off + d + 0]) + cb[shift_off + d + 0];
    fm.y = xn[1] * (1.f + cb[scale_off + d + 1]) + cb[shift_off + d + 1];
    fm.z = xn[2] * (1.f + cb[scale_off + d + 2]) + cb[shift_off + d + 2];
    fm.w = xn[3] * (1.f + cb[scale_off + d + 3]) + cb[shift_off + d + 3];
    if (out_norm) *reinterpret_cast<float4*>(out_norm + base) = fn;
    if (out_mod)  *reinterpret_cast<float4*>(out_mod + base)  = fm;
    if (ws_mod) {
        ushort4 um = {f2b(fm.x), f2b(fm.y), f2b(fm.z), f2b(fm.w)};
        *reinterpret_cast<ushort4*>(ws_mod + base) = um;
    }
}

// ------------------------------------------------------------ MFMA GEMM (m97)
// MODE 0: qkv: Q,K parts -> Cb; V part -> VTg[b][h][dh][s] (transposed store)
// MODE 1: x1b = bf16(f(Xres) + gate_msa * C)
// MODE 2: Cb = bf16(gelu_exact(C))
// MODE 3: outf = f(x1b) + gate_mlp * C
template <int MODE>
__global__ __launch_bounds__(256, 2)
void gemm_kernel(const u16* __restrict__ A, const u16* __restrict__ BT,
                 const void* __restrict__ bias, const float* __restrict__ bias32,
                 const int* __restrict__ flag, int M, int N, int K,
                 u16* __restrict__ Cb, const void* __restrict__ Xres,
                 const float* __restrict__ cmodf, int gate_off,
                 u16* __restrict__ x1b, float* __restrict__ outf,
                 u16* __restrict__ VTg) {
    __shared__ __align__(16) u16 Al[128 * 32];
    __shared__ __align__(16) u16 Bl[128 * 32];
    const int tid = threadIdx.x, lane = tid & 63, w = tid >> 6;
    const int m0 = blockIdx.y * 128, n0 = blockIdx.x * 128;
    const int wr = (w & 1) * 64, wc = (w >> 1) * 64;
    const int l15 = lane & 15, kq = (lane >> 4) << 3;
    const int srow = lane >> 2, skoff = (lane & 3) * 8;
    f32x4 acc[4][4] = {};
    for (int k0 = 0; k0 < K; k0 += 32) {
        __syncthreads();
#pragma unroll
        for (int c = 0; c < 2; ++c) {
            const int chunk = w * 2 + c;
            const int row = chunk * 16 + srow;
            gload16(A + (size_t)(m0 + row) * K + k0 + skoff, &Al[chunk * 512]);
            gload16(BT + (size_t)(n0 + row) * K + k0 + skoff, &Bl[chunk * 512]);
        }
        __syncthreads();
        bf16x8 afr[4], bfr[4];
#pragma unroll
        for (int i = 0; i < 4; ++i)
            afr[i] = *(const bf16x8*)&Al[(wr + i * 16 + l15) * 32 + kq];
#pragma unroll
        for (int j = 0; j < 4; ++j)
            bfr[j] = *(const bf16x8*)&Bl[(wc + j * 16 + l15) * 32 + kq];
#pragma unroll
        for (int i = 0; i < 4; ++i)
#pragma unroll
            for (int j = 0; j < 4; ++j)
                acc[i][j] = __builtin_amdgcn_mfma_f32_16x16x32_bf16(
                    afr[i], bfr[j], acc[i][j], 0, 0, 0);
    }
    const int isf = flag[0];
    const int rbase = (lane >> 4) << 2;
#pragma unroll
    for (int i = 0; i < 4; ++i) {
#pragma unroll
        for (int j = 0; j < 4; ++j) {
            const int colbase = n0 + wc + j * 16;
            const int col = colbase + l15;
            float bv;
            if (MODE == 0) bv = bias32[col];
            else bv = isf ? ((const float*)bias)[col] : b2f(((const u16*)bias)[col]);
#pragma unroll
            for (int r = 0; r < 4; ++r) {
                const int m = m0 + wr + i * 16 + rbase + r;
                float t = acc[i][j][r] + bv;
                const size_t idx = (size_t)m * N + col;
                if (MODE == 0) {
                    if (colbase >= 2048) {   // V part: store transposed
                        const int hh = (col - 2048) >> 6, dh = (col - 2048) & 63;
                        const int bb = m >> 10, ss = m & 1023;
                        VTg[(((size_t)bb * 16 + hh) * 64 + dh) * 1024 + ss] = f2b(t);
                    } else {
                        Cb[idx] = f2b(t);
                    }
                } else if (MODE == 1) {
                    const int bb = m >> 10;
                    float g = cmodf[bb * 6144 + gate_off + col];
                    float xr = isf ? ((const float*)Xres)[idx]
                                   : b2f(((const u16*)Xres)[idx]);
                    x1b[idx] = f2b(xr + g * t);
                } else if (MODE == 2) {
                    float gl = 0.5f * t * (1.f + erff(t * 0.70710678118654752f));
                    Cb[idx] = f2b(gl);
                } else {
                    const int bb = m >> 10;
                    float g = cmodf[bb * 6144 + gate_off + col];
                    outf[idx] = b2f(x1b[idx]) + g * t;
                }
            }
        }
    }
}

// --------------------------------------------- fused flash attention (64-row Q)
// QKV[8192][3072] (Q+0, K+1024; V region unused), VT[b][h][64][1024].
__global__ __launch_bounds__(256)
void attn_kernel(const u16* __restrict__ QKV, const u16* __restrict__ VT,
                 u16* __restrict__ Y) {
    __shared__ __align__(16) u16 qS[64 * 72];
    __shared__ __align__(16) u16 kS[128 * 72];
    __shared__ __align__(16) u16 vS[64 * 132];   // [dh][key]
    __shared__ __align__(16) u16 pS[64 * 132];   // [q][key]
    const int tid = threadIdx.x, lane = tid & 63, w = tid >> 6;
    const int l15 = lane & 15, quad = lane >> 4;
    const int kq = quad * 8, rbase = quad * 4;
    const int qt = blockIdx.x, h = blockIdx.y, b = blockIdx.z;
    const int s0 = qt * 64;
    const size_t rowbase = (size_t)b * 1024;
    const int hq = h * 64, hk = 1024 + h * 64;
    const u16* vtg = VT + ((size_t)b * 16 + h) * 64 * 1024;
#pragma unroll
    for (int it = 0; it < 2; ++it) {
        int idx = it * 256 + tid;            // 512 chunks
        int r = idx >> 3, ch = idx & 7;
        *(bf16x8*)&qS[r * 72 + ch * 8] =
            *(const bf16x8*)(QKV + (rowbase + s0 + r) * 3072 + hq + ch * 8);
    }
    __syncthreads();
    bf16x8 qa[2];
#pragma unroll
    for (int ks = 0; ks < 2; ++ks)
        qa[ks] = *(const bf16x8*)&qS[(w * 16 + l15) * 72 + ks * 32 + kq];
    f32x4 accO[4] = {};
    float m_i[4], l_i[4];
#pragma unroll
    for (int r = 0; r < 4; ++r) { m_i[r] = -3e38f; l_i[r] = 0.f; }
    for (int kt = 0; kt < 8; ++kt) {
        __syncthreads();                     // prev tile fully consumed
#pragma unroll
        for (int it = 0; it < 4; ++it) {     // K tile 128x64 -> kS
            int idx = it * 256 + tid;
            int r = idx >> 3, ch = idx & 7;
            *(bf16x8*)&kS[r * 72 + ch * 8] =
                *(const bf16x8*)(QKV + (rowbase + kt * 128 + r) * 3072 + hk + ch * 8);
        }
#pragma unroll
        for (int it = 0; it < 4; ++it) {     // V^T tile 64x128 -> vS (coalesced)
            int idx = it * 256 + tid;        // 1024 chunks
            int dh = idx >> 4, kc = idx & 15;
            *(bf16x8*)&vS[dh * 132 + kc * 8] =
                *(const bf16x8*)(vtg + (size_t)dh * 1024 + kt * 128 + kc * 8);
        }
        __syncthreads();
        // S = Q K^T
        f32x4 s[8];
#pragma unroll
        for (int nt = 0; nt < 8; ++nt) {
            f32x4 a = {};
#pragma unroll
            for (int ks = 0; ks < 2; ++ks) {
                bf16x8 kb = *(const bf16x8*)&kS[(nt * 16 + l15) * 72 + ks * 32 + kq];
                a = __builtin_amdgcn_mfma_f32_16x16x32_bf16(qa[ks], kb, a, 0, 0, 0);
            }
            s[nt] = a;
        }
        float alpha[4];
#pragma unroll
        for (int r = 0; r < 4; ++r) {
            float mx = fmaxf(fmaxf(fmaxf(s[0][r], s[1][r]), fmaxf(s[2][r], s[3][r])),
                             fmaxf(fmaxf(s[4][r], s[5][r]), fmaxf(s[6][r], s[7][r])));
            mx = fmaxf(mx, __shfl_xor(mx, 1));
            mx = fmaxf(mx, __shfl_xor(mx, 2));
            mx = fmaxf(mx, __shfl_xor(mx, 4));
            mx = fmaxf(mx, __shfl_xor(mx, 8));
            float mn = fmaxf(m_i[r], mx);
            alpha[r] = __expf(m_i[r] - mn);
            m_i[r] = mn;
            float rs = 0.f;
#pragma unroll
            for (int nt = 0; nt < 8; ++nt) {
                float p = __expf(s[nt][r] - mn);
                s[nt][r] = p;
                rs += p;
            }
            rs += __shfl_xor(rs, 1);
            rs += __shfl_xor(rs, 2);
            rs += __shfl_xor(rs, 4);
            rs += __shfl_xor(rs, 8);
            l_i[r] = l_i[r] * alpha[r] + rs;
        }
        // P -> LDS, direct scalar u16 stores (2-way banks with 132 stride)
#pragma unroll
        for (int nt = 0; nt < 8; ++nt)
#pragma unroll
            for (int r = 0; r < 4; ++r)
                pS[(w * 16 + rbase + r) * 132 + nt * 16 + l15] = f2b(s[nt][r]);
        __syncthreads();
#pragma unroll
        for (int dt = 0; dt < 4; ++dt)
#pragma unroll
            for (int r = 0; r < 4; ++r) accO[dt][r] *= alpha[r];
        bf16x8 pa[4];
#pragma unroll
        for (int ks = 0; ks < 4; ++ks)
            pa[ks] = *(const bf16x8*)&pS[(w * 16 + l15) * 132 + ks * 32 + kq];
#pragma unroll
        for (int dt = 0; dt < 4; ++dt) {
#pragma unroll
            for (int ks = 0; ks < 4; ++ks) {
                bf16x8 vb = *(const bf16x8*)&vS[(dt * 16 + l15) * 132 + ks * 32 + kq];
                accO[dt] = __builtin_amdgcn_mfma_f32_16x16x32_bf16(pa[ks], vb, accO[dt], 0, 0, 0);
            }
        }
    }
#pragma unroll
    for (int dt = 0; dt < 4; ++dt)
#pragma unroll
        for (int r = 0; r < 4; ++r) {
            float o = accO[dt][r] / l_i[r];
            Y[(rowbase + s0 + w * 16 + rbase + r) * 1024 + h * 64 + dt * 16 + l15] = f2b(o);
        }
}

// ----------------------------------------------------------------- launch
extern "C" void kernel_launch(void* const* d_in, const int* in_sizes, int n_in,
                              void* d_out, int out_size, void* d_ws, size_t ws_size,
                              hipStream_t stream) {
    const void* x      = d_in[0];
    const void* c      = d_in[1];
    const void* w_mod  = d_in[2];
    const void* b_mod  = d_in[3];
    const void* w_q    = d_in[4];
    const void* b_q    = d_in[5];
    const void* w_k    = d_in[6];
    const void* b_k    = d_in[7];
    const void* w_v    = d_in[8];
    const void* b_v    = d_in[9];
    const void* w_attn = d_in[10];
    const void* b_attn = d_in[11];
    const void* w_fc1  = d_in[12];
    const void* b_fc1  = d_in[13];
    const void* w_fc2  = d_in[14];
    const void* b_fc2  = d_in[15];

    float* out = (float*)d_out;
    float* out_xout  = out;
    float* out_norm  = out + 8388608;
    float* out_mod   = out + 16777216;
    float* out_shift = out + 25165824;
    float* out_scale = out + 25174016;
    float* out_cmod  = out + 25182208;
    float* out_cact  = out + 25231360;

    char* ws = (char*)d_ws;
    float* cactf   = (float*)(ws + 0);
    float* cmodf   = (float*)(ws + 32768);
    int*   flag    = (int*)(ws + 229376);
    float* bqkv    = (float*)(ws + 230400);
    float* partial = (float*)(ws + 262144);      // 1.57 MB
    u16* wqkvT = (u16*)(ws + 2097152);           // 6 MB
    u16* waT   = (u16*)(ws + 8388608);           // 2 MB
    u16* wf1T  = (u16*)(ws + 10485760);          // 8 MB
    u16* wf2T  = (u16*)(ws + 18874368);          // 8 MB  (end 27262976)
    u16* xmod  = (u16*)(ws + 27262976);          // 16 MB
    u16* yw    = xmod;                           // alias: xmod dead after qkv GEMM
    u16* qkv   = (u16*)(ws + 44040192);          // 48 MB (V third unused)
    u16* xmod2 = qkv;                            // alias: qkv dead after attn
    u16* vtg   = (u16*)(ws + 94371840);          // 16 MB
    u16* hw    = (u16*)(ws + 60817408);          // 64 MB, overlays dead qkv-tail+vtg
    u16* x1b   = (u16*)(ws + 127926272);         // 16 MB (end ~138 MiB)

    sniff_kernel<<<1, 256, 0, stream>>>((const u16*)w_q, flag);
    transpose_w4_kernel<<<dim3(32, 32, 4), 256, 0, stream>>>(w_q, w_k, w_v, w_attn,
        flag, wqkvT, waT);
    transpose_w_kernel<<<dim3(128, 32), 256, 0, stream>>>(w_fc1, flag, 1024, 4096, wf1T);
    transpose_w_kernel<<<dim3(32, 128), 256, 0, stream>>>(w_fc2, flag, 4096, 1024, wf2T);
    biasqkv_kernel<<<12, 256, 0, stream>>>(b_q, b_k, b_v, flag, bqkv);

    silu_kernel<<<32, 256, 0, stream>>>(c, flag, cactf, out_cact);
    cmod1_kernel<<<dim3(24, 8), 256, 0, stream>>>(cactf, w_mod, flag, partial);
    cmod2_kernel<<<24, 256, 0, stream>>>(partial, b_mod, flag, cmodf,
                                         out_cmod, out_shift, out_scale);
    ln_mod_kernel<<<8192, 256, 0, stream>>>(x, flag, 2, cmodf, 0, 1024,
                                            out_norm, out_mod, xmod);
    gemm_kernel<0><<<dim3(24, 64), 256, 0, stream>>>(xmod, wqkvT, nullptr, bqkv,
        flag, 8192, 3072, 1024, qkv, nullptr, nullptr, 0, nullptr, nullptr, vtg);
    attn_kernel<<<dim3(16, 16, 8), 256, 0, stream>>>(qkv, vtg, yw);
    gemm_kernel<1><<<dim3(8, 64), 256, 0, stream>>>(yw, waT, b_attn, nullptr,
        flag, 8192, 1024, 1024, nullptr, x, cmodf, 2048, x1b, nullptr, nullptr);
    ln_mod_kernel<<<8192, 256, 0, stream>>>(x1b, flag, 0, cmodf, 3072, 4096,
                                            nullptr, nullptr, xmod2);
    gemm_kernel<2><<<dim3(32, 64), 256, 0, stream>>>(xmod2, wf1T, b_fc1, nullptr,
        flag, 8192, 4096, 1024, hw, nullptr, nullptr, 0, nullptr, nullptr, nullptr);
    gemm_kernel<3><<<dim3(8, 64), 256, 0, stream>>>(hw, wf2T, b_fc2, nullptr,
        flag, 8192, 1024, 4096, nullptr, nullptr, cmodf, 5120, x1b, out_xout, nullptr);

    (void)in_sizes; (void)n_in; (void)out_size; (void)ws_size;
}